// Round 7
// baseline (291.315 us; speedup 1.0000x reference)
//
#include <hip/hip_runtime.h>
#include <math.h>

// Pe_local_based_attention: B=4, H=8, N=4096, K=32, D=8 (fp32)
// R6: wave-turnover fix. R0/R3/R5 (structurally different, same 65536
// one-shot waves) all ran at exactly ~101.5us, even with L3-resident data
// -> duration is per-wave-slot bound, not BW/structure bound.
// Now: 2048 blocks x 256 thr = 8192 waves (8x fewer); each 32-lane group
// loops over 8 consecutive triples with prefetch-distance-1 software
// pipeline (loads of i+1 in flight during compute of i). Loop invariants
// (h, weights, v_xyz re_xyz row) hoisted. launch_bounds(256,4) caps VGPR
// at 128 to keep ~2 iterations of loads in flight without spilling.

#define GROUPS_PER_BLOCK 8   // 256 threads / 32
#define TRIP_PER_GROUP   8
#define NBLOCKS          2048 // 131072 triples / (8 groups * 8 triples)

struct Tri {
    float k0,k1,k2,k3,k4,k5,k6,k7;  // k_mat column k
    float4 qa, qb;                   // q row (broadcast)
    float r0,r1,r2;                  // re_xyz for score bias
    float s0,s1,s2;                  // re_xyz for v_xyz
    float4 v0, v1;                   // v row k
};

__device__ __forceinline__ Tri load_tri(
    const float* __restrict__ q, const float* __restrict__ k_mat,
    const float* __restrict__ v, const float* __restrict__ re_xyz,
    int t, int b, int n, int k, const float* __restrict__ rxc_row, int i)
{
    Tri x;
    const float* kb = k_mat + (size_t)t * 256 + k;
    x.k0 = kb[0];   x.k1 = kb[32];  x.k2 = kb[64];  x.k3 = kb[96];
    x.k4 = kb[128]; x.k5 = kb[160]; x.k6 = kb[192]; x.k7 = kb[224];
    const float4* qp = (const float4*)(q + (size_t)t * 8);
    x.qa = qp[0]; x.qb = qp[1];
    const float* rb = re_xyz + ((size_t)((b << 12) + n) * 32 + k) * 3;
    x.r0 = rb[0]; x.r1 = rb[1]; x.r2 = rb[2];
    const float* rc = rxc_row + 12 * i;   // k2 = 4*i + (k>>3)
    x.s0 = rc[0]; x.s1 = rc[1]; x.s2 = rc[2];
    const float4* vb = (const float4*)(v + (size_t)t * 256 + (k << 3));
    x.v0 = vb[0]; x.v1 = vb[1];
    return x;
}

__global__ __launch_bounds__(256, 4) void pe_attn_kernel(
    const float* __restrict__ q,       // [B,H,N,1,D]
    const float* __restrict__ k_mat,   // [B,H,N,D,K]
    const float* __restrict__ v,       // [B,H,N,K,D]
    const float* __restrict__ re_xyz,  // [B,N,K,3]
    const float* __restrict__ w1,      // [3,H]
    const float* __restrict__ b1,      // [H]
    const float* __restrict__ w2,      // [3,64]
    const float* __restrict__ b2,      // [64]
    float* __restrict__ out)           // [B,N,H,D]
{
    const int tid = threadIdx.x;
    const int k   = tid & 31;
    const int g   = blockIdx.x * GROUPS_PER_BLOCK + (tid >> 5);
    const int t0  = g * TRIP_PER_GROUP;       // 8-aligned
    const int b   = t0 >> 15;                 // H*N = 32768
    const int rem0= t0 & 32767;
    const int h   = rem0 >> 12;               // const over group (4096%8==0)
    const int n0  = rem0 & 4095;              // 8-aligned
    const int n2  = rem0 >> 3;                // const over group

    // ---- loop-invariant loads (hoisted) ----
    const float wq0 = w1[h], wq1 = w1[8 + h], wq2 = w1[16 + h], bq = b1[h];
    const int c0 = (k & 7) << 3;
    const float4 wr0a = ((const float4*)(w2 + c0))[0];
    const float4 wr0b = ((const float4*)(w2 + c0))[1];
    const float4 wr1a = ((const float4*)(w2 + 64 + c0))[0];
    const float4 wr1b = ((const float4*)(w2 + 64 + c0))[1];
    const float4 wr2a = ((const float4*)(w2 + 128 + c0))[0];
    const float4 wr2b = ((const float4*)(w2 + 128 + c0))[1];
    const float4 bba  = ((const float4*)(b2 + c0))[0];
    const float4 bbb  = ((const float4*)(b2 + c0))[1];
    // v_xyz re_xyz row base: row (b*4096 + n2), column start (k>>3)
    const float* rxc_row = re_xyz + ((size_t)((b << 12) + n2) * 32 + (k >> 3)) * 3;

    Tri cur = load_tri(q, k_mat, v, re_xyz, t0, b, n0, k, rxc_row, 0);

    #pragma unroll
    for (int i = 0; i < TRIP_PER_GROUP; ++i) {
        Tri nxt;
        if (i < TRIP_PER_GROUP - 1)
            nxt = load_tri(q, k_mat, v, re_xyz, t0 + i + 1, b, n0 + i + 1, k,
                           rxc_row, i + 1);

        // ---- energy + bias, scaled; exp (max-free: |e| small, fp32-safe) ----
        float e = cur.qa.x * cur.k0 + cur.qa.y * cur.k1
                + cur.qa.z * cur.k2 + cur.qa.w * cur.k3
                + cur.qb.x * cur.k4 + cur.qb.y * cur.k5
                + cur.qb.z * cur.k6 + cur.qb.w * cur.k7;
        e += cur.r0 * wq0 + cur.r1 * wq1 + cur.r2 * wq2 + bq;
        e *= 0.35355339059327373f;
        const float p = __expf(e);

        // ---- softmax denominator: 5-shuffle butterfly ----
        float s = p;
        #pragma unroll
        for (int off = 16; off; off >>= 1) s += __shfl_xor(s, off);

        // ---- weighted values (divide deferred) ----
        float pd[8];
        pd[0] = p * (cur.v0.x + cur.s0*wr0a.x + cur.s1*wr1a.x + cur.s2*wr2a.x + bba.x);
        pd[1] = p * (cur.v0.y + cur.s0*wr0a.y + cur.s1*wr1a.y + cur.s2*wr2a.y + bba.y);
        pd[2] = p * (cur.v0.z + cur.s0*wr0a.z + cur.s1*wr1a.z + cur.s2*wr2a.z + bba.z);
        pd[3] = p * (cur.v0.w + cur.s0*wr0a.w + cur.s1*wr1a.w + cur.s2*wr2a.w + bba.w);
        pd[4] = p * (cur.v1.x + cur.s0*wr0b.x + cur.s1*wr1b.x + cur.s2*wr2b.x + bbb.x);
        pd[5] = p * (cur.v1.y + cur.s0*wr0b.y + cur.s1*wr1b.y + cur.s2*wr2b.y + bbb.y);
        pd[6] = p * (cur.v1.z + cur.s0*wr0b.z + cur.s1*wr1b.z + cur.s2*wr2b.z + bbb.z);
        pd[7] = p * (cur.v1.w + cur.s0*wr0b.w + cur.s1*wr1b.w + cur.s2*wr2b.w + bbb.w);

        // ---- fold-reduce: 32-lane sum narrowing 8 -> 1; lane holds d=(k>>2)&7 ----
        {
            const bool hb = (k & 16) != 0;
            #pragma unroll
            for (int j = 0; j < 4; ++j) {
                float send = hb ? pd[j] : pd[j + 4];
                float recv = __shfl_xor(send, 16);
                pd[j] = (hb ? pd[j + 4] : pd[j]) + recv;
            }
        }
        {
            const bool hb = (k & 8) != 0;
            #pragma unroll
            for (int j = 0; j < 2; ++j) {
                float send = hb ? pd[j] : pd[j + 2];
                float recv = __shfl_xor(send, 8);
                pd[j] = (hb ? pd[j + 2] : pd[j]) + recv;
            }
        }
        {
            const bool hb = (k & 4) != 0;
            float send = hb ? pd[0] : pd[1];
            float recv = __shfl_xor(send, 4);
            pd[0] = (hb ? pd[1] : pd[0]) + recv;
        }
        pd[0] += __shfl_xor(pd[0], 2);
        pd[0] += __shfl_xor(pd[0], 1);

        if ((k & 3) == 0) {
            const int d = (k >> 2) & 7;
            out[((size_t)((b << 12) + (n0 + i)) * 8 + h) * 8 + d] =
                pd[0] * __builtin_amdgcn_rcpf(s);
        }

        cur = nxt;
    }
}

extern "C" void kernel_launch(void* const* d_in, const int* in_sizes, int n_in,
                              void* d_out, int out_size, void* d_ws, size_t ws_size,
                              hipStream_t stream) {
    const float* q      = (const float*)d_in[0];
    const float* k_mat  = (const float*)d_in[1];
    const float* v      = (const float*)d_in[2];
    const float* re_xyz = (const float*)d_in[3];
    const float* w1     = (const float*)d_in[4];
    const float* b1     = (const float*)d_in[5];
    const float* w2     = (const float*)d_in[6];
    const float* b2     = (const float*)d_in[7];
    float* out = (float*)d_out;

    dim3 grid(NBLOCKS), block(256);
    hipLaunchKernelGGL(pe_attn_kernel, grid, block, 0, stream,
                       q, k_mat, v, re_xyz, w1, b1, w2, b2, out);
}